// Round 7
// baseline (218.020 us; speedup 1.0000x reference)
//
#include <hip/hip_runtime.h>

// Problem: B=4, H=8, S=2048, D=64
// out  = [B*H*S*D]  floats   (first 4,194,304 of d_out)
// p    = [B*H*S*S]  floats   (next 134,217,728 of d_out)
#define NB 4
#define NH 8
#define NS 2048
#define ND 64
#define NBH (NB * NH)

typedef float f32x4  __attribute__((ext_vector_type(4)));
typedef float f32x16 __attribute__((ext_vector_type(16)));
typedef short s16x8  __attribute__((ext_vector_type(8)));
typedef unsigned int u32;

constexpr int TQ = 128;   // q rows per block
constexpr int TK = 128;   // keys per tile
constexpr int NT = NS / TK;

// workspace layout (pmT replaces the old row-major pm; same footprint)
constexpr size_t PM_BYTES  = (size_t)NB * NS * (NS / 8);        // 2 MiB tile-major mask
constexpr size_t WSL_BYTES = 1 << 20;                           // 1 MiB row list
constexpr size_t KHL_OFF   = PM_BYTES + WSL_BYTES;
constexpr size_t KHL_BYTES = (size_t)NBH * NT * 32768;          // 16.78 MB hi+lo tiles
constexpr size_t QHI_OFF   = KHL_OFF + KHL_BYTES;
constexpr size_t QP_BYTES  = (size_t)NBH * NS * ND * 2;         // 8.39 MB per plane
constexpr size_t QLO_OFF   = QHI_OFF + QP_BYTES;
constexpr size_t WS_NEED   = QLO_OFF + QP_BYTES;                // ~36.7 MB

// f32 -> bf16 RNE bits
__device__ __forceinline__ u32 bf16_rne(u32 u) {
    return (u + 0x7FFFu + ((u >> 16) & 1u)) >> 16;
}
__device__ __forceinline__ void cvt_split(float x, u32 &hi, u32 &lo) {
    u32 h = bf16_rne(__float_as_uint(x));
    float hf = __uint_as_float(h << 16);
    lo = bf16_rne(__float_as_uint(x - hf));
    hi = h;
}

// ---------------------------------------------------------------------------
// Tile-major packed mask: word idx = ((b*16 + kt)*2048 + q)*4 + ks,
// bit j of word = (mask[b][q][kt*128 + ks*32 + j] != 0).
// One thread per word: reads 128 B coalesced, writes 4 B coalesced.
// ---------------------------------------------------------------------------
__global__ __launch_bounds__(256)
void pack_maskT_kernel(const int* __restrict__ mask, u32* __restrict__ pmT)
{
    int idx = blockIdx.x * 256 + threadIdx.x;   // 524288 words
    int ks = idx & 3;
    int q  = (idx >> 2) & 2047;
    int kt = (idx >> 13) & 15;
    int b  = idx >> 17;
    const int* mp = mask + ((size_t)b * NS + q) * NS + kt * 128 + ks * 32;
    u32 v = 0;
    #pragma unroll
    for (int i = 0; i < 8; ++i) {
        int4 a = *(const int4*)(mp + i * 4);
        v |= (u32)(a.x != 0) << (i * 4)
           | (u32)(a.y != 0) << (i * 4 + 1)
           | (u32)(a.z != 0) << (i * 4 + 2)
           | (u32)(a.w != 0) << (i * 4 + 3);
    }
    pmT[idx] = v;
}

// ---------------------------------------------------------------------------
// K split: f32 -> bf16 hi/lo planes, fragment-exact per-tile image.
// Tile image (32 KB): shorts[plane][ (dstep*2+hl)*128 + key ][8], hi=0, lo=+8192.
// ---------------------------------------------------------------------------
__global__ __launch_bounds__(256)
void ksplit_kernel(const float* __restrict__ K, short* __restrict__ khl)
{
    int idx = blockIdx.x * 256 + threadIdx.x;   // ((bh*2048 + kg)*8 + oct)
    int oct = idx & 7;
    int kg  = (idx >> 3) & 2047;
    int bh  = idx >> 14;
    const float* src = K + ((size_t)bh * NS + kg) * ND + oct * 8;
    f32x4 a = *(const f32x4*)src;
    f32x4 b = *(const f32x4*)(src + 4);
    u32 h[8], lo[8];
    cvt_split(a.x,h[0],lo[0]); cvt_split(a.y,h[1],lo[1]);
    cvt_split(a.z,h[2],lo[2]); cvt_split(a.w,h[3],lo[3]);
    cvt_split(b.x,h[4],lo[4]); cvt_split(b.y,h[5],lo[5]);
    cvt_split(b.z,h[6],lo[6]); cvt_split(b.w,h[7],lo[7]);
    union { u32 u[4]; s16x8 s; } H, L;
    #pragma unroll
    for (int e = 0; e < 4; ++e) {
        H.u[e] = h[2*e]  | (h[2*e+1]  << 16);
        L.u[e] = lo[2*e] | (lo[2*e+1] << 16);
    }
    int kt = kg >> 7, key = kg & 127, d_ = oct >> 1, hl = oct & 1;
    size_t base = (size_t)(bh * NT + kt) * 16384;        // shorts per tile
    size_t frag = (size_t)(((d_ * 2 + hl) * 128) + key) * 8;
    *(s16x8*)(khl + base + frag)        = H.s;
    *(s16x8*)(khl + base + 8192 + frag) = L.s;
}

// ---------------------------------------------------------------------------
// Q split: f32 -> bf16 hi/lo row-major planes.
// ---------------------------------------------------------------------------
__global__ __launch_bounds__(256)
void qsplit_kernel(const float* __restrict__ Q, short* __restrict__ qhi,
                   short* __restrict__ qlo)
{
    int idx = blockIdx.x * 256 + threadIdx.x;   // ((bh*2048 + q)*8 + oct)
    int oct = idx & 7;
    size_t row = (size_t)(idx >> 3);
    const float* src = Q + row * ND + oct * 8;
    f32x4 a = *(const f32x4*)src;
    f32x4 b = *(const f32x4*)(src + 4);
    u32 h[8], lo[8];
    cvt_split(a.x,h[0],lo[0]); cvt_split(a.y,h[1],lo[1]);
    cvt_split(a.z,h[2],lo[2]); cvt_split(a.w,h[3],lo[3]);
    cvt_split(b.x,h[4],lo[4]); cvt_split(b.y,h[5],lo[5]);
    cvt_split(b.z,h[6],lo[6]); cvt_split(b.w,h[7],lo[7]);
    union { u32 u[4]; s16x8 s; } H, L;
    #pragma unroll
    for (int e = 0; e < 4; ++e) {
        H.u[e] = h[2*e]  | (h[2*e+1]  << 16);
        L.u[e] = lo[2*e] | (lo[2*e+1] << 16);
    }
    *(s16x8*)(qhi + row * ND + oct * 8) = H.s;
    *(s16x8*)(qlo + row * ND + oct * 8) = L.s;
}

// ---------------------------------------------------------------------------
// qk3: barrier-free MFMA QK^T. K fragments read DIRECTLY from L2-resident
// pre-split khl (no LDS staging, no double-buffer, no per-tile barriers).
// LDS = 512 B (argb only); target <=128 VGPR -> 4 waves/SIMD.
// Frag bytes / top-2 / clean-test numerics identical to rounds 4-6.
// ---------------------------------------------------------------------------
__global__ __launch_bounds__(256, 4)
void qk3_kernel(const short* __restrict__ khl,
                const short* __restrict__ qhi,
                const short* __restrict__ qlo,
                const float* __restrict__ V,
                const u32* __restrict__ pmT,
                float* __restrict__ outp,
                float* __restrict__ p,
                int* __restrict__ wsl, int wscap)
{
    __shared__ int argb[TQ];

    const int t  = threadIdx.x;
    const int l  = t & 63;
    const int wv = t >> 6;
    const int hl = l >> 5;
    const int ln = l & 31;
    const int bh = blockIdx.x;      // head (same-head blocks -> same XCD)
    const int b  = bh >> 3;
    const int q0 = blockIdx.y * TQ;

    const float* Vb = V + (size_t)bh * NS * ND;
    float*       pb = p + ((size_t)bh * NS + q0) * NS;

    const int q = q0 + wv * 32 + ln;       // this lane's q-row

    // ---- Q fragments from pre-split planes ----
    s16x8 qh[4], ql[4];
    {
        const short* qr_h = qhi + ((size_t)bh * NS + q) * ND + hl * 8;
        const short* qr_l = qlo + ((size_t)bh * NS + q) * ND + hl * 8;
        #pragma unroll
        for (int d_ = 0; d_ < 4; ++d_) {
            qh[d_] = *(const s16x8*)(qr_h + d_ * 16);
            ql[d_] = *(const s16x8*)(qr_l + d_ * 16);
        }
    }

    const short* kh_head = khl + (size_t)(bh * NT) * 16384;
    const u32*   mrow    = pmT + (size_t)b * (NT * NS * 4) + (size_t)q * 4;

    uint4 mv = *(const uint4*)mrow;        // tile 0 mask words (coalesced)
    float m1 = -1e30f, m2 = -1e30f;
    int   i1 = 0;

    for (int kt = 0; kt < NT; ++kt) {
        uint4 mv_n = mv;
        if (kt + 1 < NT)
            mv_n = *(const uint4*)(mrow + (size_t)(kt + 1) * (NS * 4));

        const short* kb = kh_head + (size_t)kt * 16384;
        u32 mwv[4] = { mv.x >> (hl * 4), mv.y >> (hl * 4),
                       mv.z >> (hl * 4), mv.w >> (hl * 4) };

        auto top2 = [&](const f32x16& A, int ks) {
            u32 ws = mwv[ks];
            int kbase = kt * 128 + ks * 32 + hl * 4;
            #pragma unroll
            for (int r = 0; r < 16; ++r) {
                int bp = (r & 3) + 8 * (r >> 2);        // C-row pattern (m74/m101)
                float v = ((ws >> bp) & 1u) ? A[r] : -1e30f;
                bool gt = v > m1;
                m2 = gt ? m1 : fmaxf(m2, v);
                m1 = fmaxf(m1, v);
                i1 = gt ? (kbase + bp) : i1;
            }
        };

        #pragma unroll
        for (int kp = 0; kp < 2; ++kp) {
            f32x16 acc0, acc1;
            #pragma unroll
            for (int r = 0; r < 16; ++r) { acc0[r] = 0.f; acc1[r] = 0.f; }
            #pragma unroll
            for (int d_ = 0; d_ < 4; ++d_) {
                const short* fr = kb + (size_t)((((d_ * 2 + hl) * 128) + kp * 64 + ln) * 8);
                s16x8 ah0 = *(const s16x8*)fr;
                s16x8 al0 = *(const s16x8*)(fr + 8192);
                s16x8 ah1 = *(const s16x8*)(fr + 256);
                s16x8 al1 = *(const s16x8*)(fr + 8192 + 256);
                // 3-term split: Kh*Qh + Kl*Qh + Kh*Ql
                acc0 = __builtin_amdgcn_mfma_f32_32x32x16_bf16(ah0, qh[d_], acc0, 0,0,0);
                acc1 = __builtin_amdgcn_mfma_f32_32x32x16_bf16(ah1, qh[d_], acc1, 0,0,0);
                acc0 = __builtin_amdgcn_mfma_f32_32x32x16_bf16(al0, qh[d_], acc0, 0,0,0);
                acc1 = __builtin_amdgcn_mfma_f32_32x32x16_bf16(al1, qh[d_], acc1, 0,0,0);
                acc0 = __builtin_amdgcn_mfma_f32_32x32x16_bf16(ah0, ql[d_], acc0, 0,0,0);
                acc1 = __builtin_amdgcn_mfma_f32_32x32x16_bf16(ah1, ql[d_], acc1, 0,0,0);
            }
            top2(acc0, kp * 2);
            top2(acc1, kp * 2 + 1);
        }

        // zero-fill this 128x128 p tile (nontemporal, fire-and-forget)
        {
            const int tx = t & 15, ty = t >> 4;
            float* pz = pb + (size_t)(ty * 8) * NS + kt * TK + tx * 4;
            #pragma unroll
            for (int j = 0; j < 8; ++j) {
                f32x4 z = {0.f, 0.f, 0.f, 0.f};
                __builtin_nontemporal_store(z, (f32x4*)(pz + (size_t)j * NS));
                __builtin_nontemporal_store(z, (f32x4*)(pz + (size_t)j * NS + 64));
            }
        }

        mv = mv_n;
    }

    // ---- merge lane halves (disjoint key sets) ----
    {
        float om1 = __shfl_xor(m1, 32, 64);
        float om2 = __shfl_xor(m2, 32, 64);
        int   oi1 = __shfl_xor(i1, 32, 64);
        float nm1, nm2; int ni1;
        if (om1 > m1)      { nm1 = om1; ni1 = oi1; nm2 = fmaxf(om2, m1); }
        else if (om1 < m1) { nm1 = m1;  ni1 = i1;  nm2 = fmaxf(m2, om1); }
        else { nm1 = m1; ni1 = i1; nm2 = (oi1 == i1) ? fmaxf(m2, om2) : m1; }
        m1 = nm1; i1 = ni1; m2 = nm2;
    }

    if (l < 32) {
        int qrow = wv * 32 + ln;
        // score-space one-hot test + logit-gap guard for bf16-split error
        float s1 = __expf(m1) * 0.125f;
        float s2 = __expf(m2) * 0.125f;
        bool clean = (m1 > -1e29f) && (s1 < 1e38f) && (s1 - s2 > 15.0f)
                     && (m1 - m2 > 1e-3f);
        if (clean) argb[qrow] = i1;
        else if (wscap > 0) {
            argb[qrow] = -1;
            int idx = atomicAdd(wsl, 1);
            if (idx < wscap) wsl[1 + idx] = bh * NS + q0 + qrow;
        } else {
            argb[qrow] = i1;
        }
    }
    __syncthreads();   // full drain (vmcnt(0)): zero stores complete before 1.0

    // ---- emit one-hot + out = V[argmax] for clean rows ----
    #pragma unroll
    for (int s = 0; s < 8; ++s) {
        int task = t + 256 * s;          // 2048 tasks = 128 rows x 16 float4s
        int row = task >> 4, c4 = task & 15;
        int a = argb[row];
        if (a >= 0) {
            *(float4*)(outp + ((size_t)bh * NS + q0 + row) * ND + c4 * 4) =
                *(const float4*)(Vb + (size_t)a * ND + c4 * 4);
            if (c4 == 0) pb[(size_t)row * NS + a] = 1.0f;
        }
    }
}

// ---------------------------------------------------------------------------
// Round-4 kernel as fallback for mid-size ws (tile-major mask version).
// ---------------------------------------------------------------------------
__global__ __launch_bounds__(256, 2)
void qk_mfma_kernel(const float* __restrict__ Q,
                    const float* __restrict__ K,
                    const float* __restrict__ V,
                    const u32* __restrict__ pmT,
                    float* __restrict__ outp,
                    float* __restrict__ p,
                    int* __restrict__ wsl, int wscap)
{
    __shared__ __align__(16) short kbuf[2][16][1032];
    __shared__ int argb[TQ];

    const int t  = threadIdx.x;
    const int l  = t & 63;
    const int wv = t >> 6;
    const int hl = l >> 5;
    const int ln = l & 31;
    const int bh = blockIdx.x;
    const int b  = bh >> 3;
    const int q0 = blockIdx.y * TQ;

    const float* Kb = K + (size_t)bh * NS * ND;
    const float* Vb = V + (size_t)bh * NS * ND;
    float*       pb = p + ((size_t)bh * NS + q0) * NS;

    const int q = q0 + wv * 32 + ln;

    s16x8 qh[4], ql[4];
    {
        const float* Qr = Q + ((size_t)bh * NS + q) * ND + hl * 8;
        #pragma unroll
        for (int d_ = 0; d_ < 4; ++d_) {
            f32x4 v0 = *(const f32x4*)(Qr + d_ * 16);
            f32x4 v1 = *(const f32x4*)(Qr + d_ * 16 + 4);
            u32 h[8], lo[8];
            cvt_split(v0.x, h[0], lo[0]); cvt_split(v0.y, h[1], lo[1]);
            cvt_split(v0.z, h[2], lo[2]); cvt_split(v0.w, h[3], lo[3]);
            cvt_split(v1.x, h[4], lo[4]); cvt_split(v1.y, h[5], lo[5]);
            cvt_split(v1.z, h[6], lo[6]); cvt_split(v1.w, h[7], lo[7]);
            union { u32 u[4]; s16x8 s; } H, L;
            #pragma unroll
            for (int e = 0; e < 4; ++e) {
                H.u[e] = h[2*e]  | (h[2*e+1]  << 16);
                L.u[e] = lo[2*e] | (lo[2*e+1] << 16);
            }
            qh[d_] = H.s; ql[d_] = L.s;
        }
    }

    f32x4 kpref[8];
    auto load_kpref = [&](int kt_) {
        #pragma unroll
        for (int s = 0; s < 8; ++s) {
            int f = t + 256 * s; int key = f >> 4, c4 = f & 15;
            kpref[s] = *(const f32x4*)(Kb + (size_t)(kt_ * TK + key) * ND + c4 * 4);
        }
    };
    auto write_ks = [&](int bufsel) {
        #pragma unroll
        for (int s = 0; s < 8; ++s) {
            int f = t + 256 * s; int key = f >> 4, c4 = f & 15;
            int chunk = c4 >> 1, half = c4 & 1;
            f32x4 v = kpref[s];
            u32 h0,l0,h1,l1,h2,l2,h3,l3;
            cvt_split(v.x,h0,l0); cvt_split(v.y,h1,l1);
            cvt_split(v.z,h2,l2); cvt_split(v.w,h3,l3);
            uint2 H = make_uint2(h0 | (h1<<16), h2 | (h3<<16));
            uint2 L = make_uint2(l0 | (l1<<16), l2 | (l3<<16));
            *(uint2*)&kbuf[bufsel][chunk*2    ][key*8 + half*4] = H;
            *(uint2*)&kbuf[bufsel][chunk*2 + 1][key*8 + half*4] = L;
        }
    };

    load_kpref(0);
    write_ks(0);
    load_kpref(1);
    __syncthreads();

    float m1 = -1e30f, m2 = -1e30f;
    int   i1 = 0;
    int   c  = 0;
    const u32* mrow = pmT + (size_t)b * (NT * NS * 4) + (size_t)q * 4;

    for (int kt = 0; kt < NT; ++kt) {
        uint4 mvv = *(const uint4*)(mrow + (size_t)kt * (NS * 4));
        u32 mwv[4] = { mvv.x >> (hl * 4), mvv.y >> (hl * 4),
                       mvv.z >> (hl * 4), mvv.w >> (hl * 4) };

        auto top2 = [&](const f32x16& A, int ks) {
            u32 ws = mwv[ks];
            int kbase = kt * 128 + ks * 32 + hl * 4;
            #pragma unroll
            for (int r = 0; r < 16; ++r) {
                int bp = (r & 3) + 8 * (r >> 2);
                float v = ((ws >> bp) & 1u) ? A[r] : -1e30f;
                bool gt = v > m1;
                m2 = gt ? m1 : fmaxf(m2, v);
                m1 = fmaxf(m1, v);
                i1 = gt ? (kbase + bp) : i1;
            }
        };

        #pragma unroll
        for (int kp = 0; kp < 2; ++kp) {
            f32x16 acc0, acc1;
            #pragma unroll
            for (int r = 0; r < 16; ++r) { acc0[r] = 0.f; acc1[r] = 0.f; }
            #pragma unroll
            for (int d_ = 0; d_ < 4; ++d_) {
                int cpA = d_ * 4 + hl * 2;
                s16x8 ah0 = *(const s16x8*)&kbuf[c][cpA    ][(kp*64      + ln) * 8];
                s16x8 al0 = *(const s16x8*)&kbuf[c][cpA + 1][(kp*64      + ln) * 8];
                s16x8 ah1 = *(const s16x8*)&kbuf[c][cpA    ][(kp*64 + 32 + ln) * 8];
                s16x8 al1 = *(const s16x8*)&kbuf[c][cpA + 1][(kp*64 + 32 + ln) * 8];
                acc0 = __builtin_amdgcn_mfma_f32_32x32x16_bf16(ah0, qh[d_], acc0, 0,0,0);
                acc1 = __builtin_amdgcn_mfma_f32_32x32x16_bf16(ah1, qh[d_], acc1, 0,0,0);
                acc0 = __builtin_amdgcn_mfma_f32_32x32x16_bf16(al0, qh[d_], acc0, 0,0,0);
                acc1 = __builtin_amdgcn_mfma_f32_32x32x16_bf16(al1, qh[d_], acc1, 0,0,0);
                acc0 = __builtin_amdgcn_mfma_f32_32x32x16_bf16(ah0, ql[d_], acc0, 0,0,0);
                acc1 = __builtin_amdgcn_mfma_f32_32x32x16_bf16(ah1, ql[d_], acc1, 0,0,0);
            }
            top2(acc0, kp * 2);
            top2(acc1, kp * 2 + 1);
        }

        {
            const int tx = t & 15, ty = t >> 4;
            float* pz = pb + (size_t)(ty * 8) * NS + kt * TK + tx * 4;
            #pragma unroll
            for (int j = 0; j < 8; ++j) {
                f32x4 z = {0.f, 0.f, 0.f, 0.f};
                __builtin_nontemporal_store(z, (f32x4*)(pz + (size_t)j * NS));
                __builtin_nontemporal_store(z, (f32x4*)(pz + (size_t)j * NS + 64));
            }
        }

        if (kt < NT - 1) {
            write_ks(c ^ 1);
            if (kt + 2 < NT) load_kpref(kt + 2);
            __syncthreads();
            c ^= 1;
        }
    }

    {
        float om1 = __shfl_xor(m1, 32, 64);
        float om2 = __shfl_xor(m2, 32, 64);
        int   oi1 = __shfl_xor(i1, 32, 64);
        float nm1, nm2; int ni1;
        if (om1 > m1)      { nm1 = om1; ni1 = oi1; nm2 = fmaxf(om2, m1); }
        else if (om1 < m1) { nm1 = m1;  ni1 = i1;  nm2 = fmaxf(m2, om1); }
        else { nm1 = m1; ni1 = i1; nm2 = (oi1 == i1) ? fmaxf(m2, om2) : m1; }
        m1 = nm1; i1 = ni1; m2 = nm2;
    }

    if (l < 32) {
        int qrow = wv * 32 + ln;
        float s1 = __expf(m1) * 0.125f;
        float s2 = __expf(m2) * 0.125f;
        bool clean = (m1 > -1e29f) && (s1 < 1e38f) && (s1 - s2 > 15.0f)
                     && (m1 - m2 > 1e-3f);
        if (clean) argb[qrow] = i1;
        else if (wscap > 0) {
            argb[qrow] = -1;
            int idx = atomicAdd(wsl, 1);
            if (idx < wscap) wsl[1 + idx] = bh * NS + q0 + qrow;
        } else {
            argb[qrow] = i1;
        }
    }
    __syncthreads();

    #pragma unroll
    for (int s = 0; s < 8; ++s) {
        int task = t + 256 * s;
        int row = task >> 4, c4 = task & 15;
        int a = argb[row];
        if (a >= 0) {
            *(float4*)(outp + ((size_t)bh * NS + q0 + row) * ND + c4 * 4) =
                *(const float4*)(Vb + (size_t)a * ND + c4 * 4);
            if (c4 == 0) pb[(size_t)row * NS + a] = 1.0f;
        }
    }
}

// ---------------------------------------------------------------------------
// Exact reference softmax for listed rows (or ALL rows if allrows).
// ---------------------------------------------------------------------------
__global__ __launch_bounds__(256)
void slow_rows_kernel(const float* __restrict__ Q, const float* __restrict__ K,
                      const float* __restrict__ V, const int* __restrict__ mask,
                      float* __restrict__ outp, float* __restrict__ p,
                      const int* __restrict__ wsl, int wscap, int allrows)
{
    __shared__ float qr[ND];
    __shared__ float redm[4], redz[4];
    __shared__ float ol[ND];
    int n;
    if (allrows) n = NBH * NS;
    else { n = wsl[0]; if (n > wscap) n = wscap; }
    const int t = threadIdx.x;
    const int lane = t & 63, w = t >> 6;

    for (int ii = blockIdx.x; ii < n; ii += gridDim.x) {
        int row = allrows ? ii : wsl[1 + ii];
        int bh = row >> 11, qq = row & (NS - 1), b = bh >> 3;
        const float* Qr = Q + (size_t)row * ND;
        const float* Kb = K + (size_t)bh * NS * ND;
        const float* Vb = V + (size_t)bh * NS * ND;
        const int*   mr = mask + (size_t)b * NS * NS + (size_t)qq * NS;

        __syncthreads();
        if (t < 16) ((float4*)qr)[t] = ((const float4*)Qr)[t];
        if (t < ND) ol[t] = 0.f;
        __syncthreads();

        float sc[8];
        int k0 = t * 8;
        #pragma unroll
        for (int i = 0; i < 8; ++i) {
            const float* kr = Kb + (size_t)(k0 + i) * ND;
            float a = 0.f;
            for (int d = 0; d < ND; d += 4) {
                float4 kv = *(const float4*)(kr + d);
                a += qr[d] * kv.x; a += qr[d + 1] * kv.y;
                a += qr[d + 2] * kv.z; a += qr[d + 3] * kv.w;
            }
            sc[i] = mr[k0 + i] ? __expf(a) * 0.125f : -1e9f;
        }
        float m = sc[0];
        #pragma unroll
        for (int i = 1; i < 8; ++i) m = fmaxf(m, sc[i]);
        #pragma unroll
        for (int d = 1; d < 64; d <<= 1) m = fmaxf(m, __shfl_xor(m, d, 64));
        if (lane == 0) redm[w] = m;
        __syncthreads();
        m = fmaxf(fmaxf(redm[0], redm[1]), fmaxf(redm[2], redm[3]));

        float e[8]; float z = 0.f;
        #pragma unroll
        for (int i = 0; i < 8; ++i) { e[i] = __expf(sc[i] - m); z += e[i]; }
        #pragma unroll
        for (int d = 1; d < 64; d <<= 1) z += __shfl_xor(z, d, 64);
        if (lane == 0) redz[w] = z;
        __syncthreads();
        float Z = redz[0] + redz[1] + redz[2] + redz[3];
        float inv = 1.f / Z;

        float* pr = p + (size_t)row * NS + k0;
        float4 o0, o1;
        o0.x = e[0] * inv; o0.y = e[1] * inv; o0.z = e[2] * inv; o0.w = e[3] * inv;
        o1.x = e[4] * inv; o1.y = e[5] * inv; o1.z = e[6] * inv; o1.w = e[7] * inv;
        *(float4*)pr = o0; *(float4*)(pr + 4) = o1;

        #pragma unroll
        for (int i = 0; i < 8; ++i) {
            float pv = e[i] * inv;
            if (pv > 0.f) {
                const float* vr = Vb + (size_t)(k0 + i) * ND;
                for (int d = 0; d < ND; ++d) atomicAdd(&ol[d], pv * vr[d]);
            }
        }
        __syncthreads();
        if (t < ND) outp[(size_t)row * ND + t] = ol[t];
    }
}

extern "C" void kernel_launch(void* const* d_in, const int* in_sizes, int n_in,
                              void* d_out, int out_size, void* d_ws, size_t ws_size,
                              hipStream_t stream)
{
    const float* Q    = (const float*)d_in[0];
    const float* K    = (const float*)d_in[1];
    const float* V    = (const float*)d_in[2];
    const int*   mask = (const int*)d_in[3];
    float* outp = (float*)d_out;
    float* p    = outp + (size_t)NBH * NS * ND;   // p_attn after out

    if (ws_size < PM_BYTES + 8 * 1024) {
        slow_rows_kernel<<<dim3(4096), 256, 0, stream>>>(Q, K, V, mask, outp, p,
                                                         nullptr, 0, 1);
        return;
    }

    u32* pmT = (u32*)d_ws;
    dim3 grid(NBH, NS / TQ);

    if (ws_size >= WS_NEED) {
        int* wsl = (int*)((char*)d_ws + PM_BYTES);
        int wscap = (int)(WSL_BYTES / 4 - 1);
        short* khl = (short*)((char*)d_ws + KHL_OFF);
        short* qhi = (short*)((char*)d_ws + QHI_OFF);
        short* qlo = (short*)((char*)d_ws + QLO_OFF);

        hipMemsetAsync(wsl, 0, 4, stream);
        pack_maskT_kernel<<<dim3(2048), 256, 0, stream>>>(mask, pmT);
        ksplit_kernel<<<dim3(2048), 256, 0, stream>>>(K, khl);
        qsplit_kernel<<<dim3(2048), 256, 0, stream>>>(Q, qhi, qlo);

        qk3_kernel<<<grid, 256, 0, stream>>>(khl, qhi, qlo, V, pmT, outp, p,
                                             wsl, wscap);
        slow_rows_kernel<<<dim3(128), 256, 0, stream>>>(Q, K, V, mask, outp, p,
                                                        wsl, wscap, 0);
    } else {
        int* wsl = (int*)((char*)d_ws + PM_BYTES);
        size_t listBytes = ws_size - PM_BYTES;
        int wscap = (int)(listBytes / 4 - 1);
        if (wscap > 65536) wscap = 65536;

        hipMemsetAsync(wsl, 0, 4, stream);
        pack_maskT_kernel<<<dim3(2048), 256, 0, stream>>>(mask, pmT);
        qk_mfma_kernel<<<grid, 256, 0, stream>>>(Q, K, V, pmT, outp, p, wsl, wscap);
        slow_rows_kernel<<<dim3(128), 256, 0, stream>>>(Q, K, V, mask, outp, p,
                                                        wsl, wscap, 0);
    }
}